// Round 4
// baseline (99.498 us; speedup 1.0000x reference)
//
#include <hip/hip_runtime.h>

// Problem dims (fixed by reference): x shape (2,4,8,256,256) f32
#define WD 256
#define HT 256
#define DP 8
#define NBC 8
#define HW 65536       // HT*WD
#define DHW 524288     // DP*HW
#define NVOX 4194304   // NBC*DHW
#define NWAVE 16384    // NVOX/4/64 : one wave == one (bc,d,h) row
#define SLOTS 128      // >= max strict maxima per 254-interior row (127)

// Full quadratic-interp refinement for one masked voxel; overwrites the
// 4 output scalars if the final 'valid' is true (defaults already written
// by kernel A otherwise). Math transcribed 1:1 from the reference; fp
// contraction off to track the numpy reference bit-closely.
__device__ void refine_write(const float* __restrict__ x,
                             float* __restrict__ out,
                             int idx) {
#pragma clang fp contract(off)
    const int w0 = idx & 255;
    const int h0 = (idx >> 8) & 255;
    const int d0 = (idx >> 16) & 7;
    const int bc = idx >> 19;
    int d = d0, h = h0, w = w0;
    bool valid = true;
    float shx = 0.f, shy = 0.f, shs = 0.f, gds = 0.f;
    const float* xb = x + (size_t)bc * DHW;
    for (int it = 0; it < 5; ++it) {
        int dcl = min(max(d, 1), DP - 2);
        int hcl = min(max(h, 1), HT - 2);
        int wcl = min(max(w, 1), WD - 2);
        const float* q = xb + dcl * HW + hcl * WD + wcl;
        float c000 = q[0];
        float pxm = q[-1],   pxp = q[1];
        float pym = q[-WD],  pyp = q[WD];
        float psm = q[-HW],  psp = q[HW];
        float gx = 0.5f * (pxp - pxm);
        float gy = 0.5f * (pyp - pym);
        float gs = 0.5f * (psp - psm);
        float dxx = pxp - 2.0f * c000 + pxm;
        float dyy = pyp - 2.0f * c000 + pym;
        float dss = psp - 2.0f * c000 + psm;
        float dxy = 0.25f * (q[WD + 1]  - q[WD - 1]  - q[-WD + 1]  + q[-WD - 1]);
        float dxs = 0.25f * (q[HW + 1]  - q[HW - 1]  - q[-HW + 1]  + q[-HW - 1]);
        float dys = 0.25f * (q[HW + WD] - q[HW - WD] - q[-HW + WD] + q[-HW - WD]);
        float r0 = -gx, r1 = -gy, r2 = -gs;
        float cf00 = dyy * dss - dys * dys;
        float cf01 = dxy * dss - dys * dxs;
        float cf02 = dxy * dys - dyy * dxs;
        float det = dxx * cf00 - dxy * cf01 + dxs * cf02;
        bool solved = fabsf(det) > 0.0f;
        float sdet = solved ? det : 1.0f;
        float sx = (r0 * cf00 - dxy * (r1 * dss - dys * r2) + dxs * (r1 * dys - dyy * r2)) / sdet;
        float sy = (dxx * (r1 * dss - dys * r2) - r0 * cf01 + dxs * (dxy * r2 - r1 * dxs)) / sdet;
        float ss = (dxx * (dyy * r2 - r1 * dys) - dxy * (dxy * r2 - r1 * dxs) + r0 * cf02) / sdet;
        valid = valid && solved;
        if (valid) {
            shx = sx; shy = sy; shs = ss;
            gds = gx * sx + gy * sy + gs * ss;
        } else {
            sx = 0.f; sy = 0.f; ss = 0.f;
        }
        int mvx = (valid && sx > 0.6f) ? 1 : ((valid && sx < -0.6f) ? -1 : 0);
        int nw = w + mvx;
        valid = valid && (nw >= 1) && (nw <= WD - 2);
        w = min(max(nw, 0), WD - 1);
        int mvy = (valid && sy > 0.6f) ? 1 : ((valid && sy < -0.6f) ? -1 : 0);
        int nh = h + mvy;
        valid = valid && (nh >= 1) && (nh <= HT - 2);
        h = min(max(nh, 0), HT - 1);
        int mvd = (valid && ss > 0.6f) ? 1 : ((valid && ss < -0.6f) ? -1 : 0);
        int nd = d + mvd;
        valid = valid && (nd >= 1) && (nd <= DP - 2);
        d = min(max(nd, 0), DP - 1);
        if (!valid) break;                    // state can no longer change
        if (mvx == 0 && mvy == 0 && mvd == 0) // fixed point: identical iterations follow
            break;
    }
    valid = valid && (fabsf(shx) <= 1.5f) && (fabsf(shy) <= 1.5f) && (fabsf(shs) <= 1.5f);
    if (!valid) return; // defaults are the correct output

    size_t pos = (size_t)d0 * HW + (size_t)h0 * WD + (size_t)w0;
    float* cb = out + (size_t)(bc * 3) * DHW + pos;
    cb[0]         = (float)d + shs;
    cb[DHW]       = (float)w + shx;
    cb[2 * DHW]   = (float)h + shy;
    float corr = 0.5f * gds + 10.0f;
    float* yb = out + (size_t)NBC * 3 * DHW;
    yb[(size_t)bc * DHW + pos] = x[idx] + corr;
}

// Shared NMS body: computes the 4-bit strict-maxima mask for this thread's
// 4 w-consecutive voxels, and writes the default outputs. Returns -1 if the
// whole wave is a border row (wave-uniform).
__device__ __forceinline__ int nms_defaults(const float* __restrict__ x,
                                            float* __restrict__ out,
                                            int t, unsigned* mbits_out) {
    int lane = t & 63;
    int w0 = lane << 2;
    int h  = (t >> 6) & 255;
    int d  = (t >> 14) & 7;
    int bc = t >> 17;
    size_t pos = (size_t)d * HW + (size_t)h * WD + (size_t)w0;
    const float* xb = x + (size_t)bc * DHW;
    float4 c = *(const float4*)(xb + pos);

    // defaults: y = x ; coords = (d, w, h)
    float* yb = out + (size_t)NBC * 3 * DHW;
    *(float4*)(yb + (size_t)bc * DHW + pos) = c;
    float* cb = out + (size_t)(bc * 3) * DHW + pos;
    float fd = (float)d, fh = (float)h, fw = (float)w0;
    *(float4*)(cb)           = make_float4(fd, fd, fd, fd);
    *(float4*)(cb + DHW)     = make_float4(fw, fw + 1.f, fw + 2.f, fw + 3.f);
    *(float4*)(cb + 2 * DHW) = make_float4(fh, fh, fh, fh);

    // border rows can never be strict maxima (edge-replicated padding)
    if (d == 0 || d == DP - 1 || h == 0 || h == HT - 1) return -1;

    const float NEG = -3.4e38f;
    float n0 = NEG, n1 = NEG, n2 = NEG, n3 = NEG;
    const float* rowc = xb + pos;
#pragma unroll
    for (int dd = -1; dd <= 1; ++dd) {
#pragma unroll
        for (int hh = -1; hh <= 1; ++hh) {
            float4 v;
            if (dd == 0 && hh == 0) v = c;
            else v = *(const float4*)(rowc + dd * HW + hh * WD);
            float L = __shfl_up(v.w, 1);   // lane-1's last elem = x[w0-1]
            float R = __shfl_down(v.x, 1); // lane+1's first elem = x[w0+4]
            if (dd == 0 && hh == 0) {
                // center row: exclude the center element itself
                n0 = fmaxf(n0, fmaxf(L,   v.y));
                n1 = fmaxf(n1, fmaxf(v.x, v.z));
                n2 = fmaxf(n2, fmaxf(v.y, v.w));
                n3 = fmaxf(n3, fmaxf(v.z, R));
            } else {
                n0 = fmaxf(n0, fmaxf(fmaxf(L,   v.x), v.y));
                n1 = fmaxf(n1, fmaxf(fmaxf(v.x, v.y), v.z));
                n2 = fmaxf(n2, fmaxf(fmaxf(v.y, v.z), v.w));
                n3 = fmaxf(n3, fmaxf(fmaxf(v.z, v.w), R));
            }
        }
    }
    bool m0 = (c.x > n0) && (w0 > 0);            // w=0 never a max (lane 0 L garbage is fine)
    bool m1 = (c.y > n1);
    bool m2 = (c.z > n2);
    bool m3 = (c.w > n3) && (w0 + 3 < WD - 1);   // w=255 never a max
    *mbits_out = (m0 ? 1u : 0u) | (m1 ? 2u : 0u) | (m2 ? 4u : 0u) | (m3 ? 8u : 0u);
    return (bc << 19) | (d << 16) | (h << 8) | w0;
}

// Kernel A: defaults + NMS + per-wave compaction into private slot regions.
// No global atomics (round-1 counters: the single-address atomicAdd chain
// cost ~160us), no refine code (keeps VGPR low for the BW-bound bulk).
__global__ __launch_bounds__(256) void nms_compact(const float* __restrict__ x,
                                                   float* __restrict__ out,
                                                   int* __restrict__ cnt,
                                                   int* __restrict__ list) {
    int t = blockIdx.x * 256 + threadIdx.x;   // [0, NVOX/4)
    int lane = t & 63;
    int wid = t >> 6;                          // wave id == (bc,d,h) row id
    unsigned mbits = 0;
    int vidx = nms_defaults(x, out, t, &mbits);
    if (vidx < 0) {                            // wave-uniform border exit
        if (lane == 0) cnt[wid] = 0;           // ws is poisoned: must write
        return;
    }
    // wave-local compaction: 4 ballots (one per bit position) + popc prefix.
    unsigned long long lt = (lane == 0) ? 0ull : (~0ull >> (64 - lane));
    unsigned long long b0 = __ballot(mbits & 1u);
    unsigned long long b1 = __ballot(mbits & 2u);
    unsigned long long b2 = __ballot(mbits & 4u);
    unsigned long long b3 = __ballot(mbits & 8u);
    int prefix = __popcll(b0 & lt) + __popcll(b1 & lt) +
                 __popcll(b2 & lt) + __popcll(b3 & lt);
    int total  = __popcll(b0) + __popcll(b1) + __popcll(b2) + __popcll(b3);
    if (lane == 0) cnt[wid] = total;           // total <= 127 < SLOTS always
    int base = wid * SLOTS + prefix;
    while (mbits) {
        int i = __ffs(mbits) - 1;
        mbits &= mbits - 1;
        list[base++] = vidx + i;
    }
}

// Kernel B: one thread per slot. Lanes of a wave share one source row ->
// stencil loads stay L1-hot (unlike round-1's atomic-ordered scatter).
__global__ __launch_bounds__(256) void refine_list(const float* __restrict__ x,
                                                   float* __restrict__ out,
                                                   const int* __restrict__ cnt,
                                                   const int* __restrict__ list) {
    int i = blockIdx.x * 256 + threadIdx.x;    // [0, NWAVE*SLOTS)
    int wid = i >> 7;                           // SLOTS == 128
    int slot = i & (SLOTS - 1);
    if (slot < cnt[wid])
        refine_write(x, out, list[wid * SLOTS + slot]);
}

// Fallback single-kernel path (round-2 fused) if d_ws is too small.
__global__ __launch_bounds__(256) void fused(const float* __restrict__ x,
                                             float* __restrict__ out) {
    int t = blockIdx.x * 256 + threadIdx.x;
    unsigned mbits = 0;
    int vidx = nms_defaults(x, out, t, &mbits);
    if (vidx < 0) return;
    while (mbits) {
        int i = __ffs(mbits) - 1;
        mbits &= mbits - 1;
        refine_write(x, out, vidx + i);
    }
}

extern "C" void kernel_launch(void* const* d_in, const int* in_sizes, int n_in,
                              void* d_out, int out_size, void* d_ws, size_t ws_size,
                              hipStream_t stream) {
    const float* x = (const float*)d_in[0];
    float* out = (float*)d_out;
    const size_t need = (size_t)NWAVE * 4 + (size_t)NWAVE * SLOTS * 4; // 64KB + 8MB
    if (ws_size >= need) {
        int* cnt  = (int*)d_ws;
        int* list = (int*)((char*)d_ws + (size_t)NWAVE * 4);
        nms_compact<<<NVOX / 4 / 256, 256, 0, stream>>>(x, out, cnt, list);
        refine_list<<<NWAVE * SLOTS / 256, 256, 0, stream>>>(x, out, cnt, list);
    } else {
        fused<<<NVOX / 4 / 256, 256, 0, stream>>>(x, out);
    }
}